// Round 3
// baseline (567.711 us; speedup 1.0000x reference)
//
#include <hip/hip_runtime.h>
#include <math.h>

// Problem constants
#define BATCH   8192
#define IN_DIM  1024
#define LAT     256
#define NEMB    8192

#define TAU 3e-3f   // flag margin; score err sigma ~2.8e-4 (fp16-B rounding), TAU ~ 10 sigma

typedef _Float16 f16x8 __attribute__((ext_vector_type(8)));
typedef _Float16 f16x4 __attribute__((ext_vector_type(4)));
typedef float f32x16_t __attribute__((ext_vector_type(16)));

typedef __attribute__((address_space(1))) const unsigned int gu32_t;
typedef __attribute__((address_space(3))) unsigned int lu32_t;

// order-preserving float<->u32 transform
__device__ __forceinline__ unsigned int ford(float x) {
  unsigned int u = __float_as_uint(x);
  return (u & 0x80000000u) ? ~u : (u | 0x80000000u);
}
__device__ __forceinline__ float funord(unsigned int t) {
  unsigned int u = (t & 0x80000000u) ? (t & 0x7FFFFFFFu) : ~t;
  return __uint_as_float(u);
}

// ---------------------------------------------------------------------------
// Per-code inverse norms: one wave per embedding row.
// ---------------------------------------------------------------------------
__global__ __launch_bounds__(256) void emb_norms(
    const float* __restrict__ emb, float* __restrict__ inv_norm) {
  int row = blockIdx.x * 4 + (threadIdx.x >> 6);
  int lane = threadIdx.x & 63;
  const float* p = emb + (size_t)row * LAT;
  float s = 0.f;
#pragma unroll
  for (int t = 0; t < 4; ++t) {
    float v = p[lane + 64 * t];
    s += v * v;
  }
#pragma unroll
  for (int off = 32; off; off >>= 1) s += __shfl_xor(s, off);
  if (lane == 0) inv_norm[row] = 1.0f / sqrtf(s);
}

// ---------------------------------------------------------------------------
// Split fp32 [R x K] (optionally scaled per-row) into fp16 hi (+ optional lo)
// in MFMA-32x32x16 fragment order:
//   frag block g=(tile,kb): lane l -> elem [tile*32+(l&31)][kb*16+(l>>5)*8+j]
//   stored at dst[(g*64+l)*8 + j]; lo at dst + lo_off (= R*K) if write_lo.
// One wave per 32x16 block; grid = (R/32)*(K/16)/4 blocks of 256.
// ---------------------------------------------------------------------------
__global__ __launch_bounds__(256) void split16(
    const float* __restrict__ src, const float* __restrict__ inv_norm,
    _Float16* __restrict__ dst, size_t lo_off, int KD, int write_lo) {
  int gw = (blockIdx.x * 256 + threadIdx.x) >> 6;
  int l = threadIdx.x & 63;
  int tile = gw / KD, kb = gw % KD;
  int row = tile * 32 + (l & 31);
  int k = kb * 16 + (l >> 5) * 8;
  const float* p = src + (size_t)row * (KD * 16) + k;
  float scale = inv_norm ? inv_norm[row] : 1.0f;
  f16x8 h, lo;
#pragma unroll
  for (int j = 0; j < 8; ++j) {
    float v = p[j] * scale;
    _Float16 hh = (_Float16)v;
    h[j] = hh;
    lo[j] = (_Float16)(v - (float)hh);
  }
  size_t o = ((size_t)gw * 64 + l) * 8;
  *(f16x8*)(dst + o) = h;
  if (write_lo) *(f16x8*)(dst + lo_off + o) = lo;
}

// ---------------------------------------------------------------------------
// Split-fp16 MFMA GEMM: C[M][N] = A[M][K] @ Bw[N][K]^T + bias[N].
// A: fp32, converted to hi/lo fp16 in-kernel during LDS staging (ds_write).
// B: pre-split fragment-order fp16 (hi at Bfrag, lo at Bfrag+b_lo_off),
//    staged via global_load_lds width=16.
// Block 64x64, 4 waves, wave w -> (m-tile w&1, n-tile w>>1), K slices of 64.
// 3 MFMAs per k-step: ah*bh + ah*bl + al*bh (residual ~2^-22).
// ---------------------------------------------------------------------------
__global__ __launch_bounds__(256) void gemm16(
    const float* __restrict__ A, const _Float16* __restrict__ Bfrag,
    size_t b_lo_off, const float* __restrict__ bias, float* __restrict__ C,
    int M, int N, int K) {
  __shared__ char lds[32768];  // A frags [0,16K): chunk=((mt*2+prec)*4+ks); B at 16K
  const int tid = threadIdx.x;
  const int l = tid & 63;
  const int w = tid >> 6;
  const int mt = w & 1, nt = w >> 1;
  const int rb = blockIdx.y * 64, cb = blockIdx.x * 64;
  const int KD = K >> 4;

  f32x16_t acc = (f32x16_t)0.0f;

  for (int s = 0; s < (K >> 6); ++s) {
    // stage B from fragment buffer
#pragma unroll
    for (int i = 0; i < 4; ++i) {
      int c = i * 4 + w;  // 0..15: ((bnt*2+prec)*4+ks)
      int bnt = c >> 3, prec = (c >> 2) & 1, ks = c & 3;
      int tile = (cb >> 5) + bnt, ksg = s * 4 + ks;
      const _Float16* src = Bfrag + (size_t)prec * b_lo_off +
                            ((size_t)(tile * KD + ksg) * 64 + l) * 8;
      __builtin_amdgcn_global_load_lds((gu32_t*)src,
                                       (lu32_t*)(lds + 16384 + (c << 10) + l * 16),
                                       16, 0, 0);
    }
    // stage A: load fp32, split to hi/lo fp16, ds_write in frag order
#pragma unroll
    for (int t = 0; t < 4; ++t) {
      int flat = t * 256 + tid;
      int r = flat >> 4, c4 = flat & 15;
      float4 v = *(const float4*)&A[(size_t)(rb + r) * K + s * 64 + 4 * c4];
      int kk = 4 * c4;
      int ks = kk >> 4, j = kk & 7;
      int lane2 = (r & 31) + 32 * ((kk >> 3) & 1);
      int mtt = r >> 5;
      f16x4 hv, lv;
      float vv[4] = {v.x, v.y, v.z, v.w};
#pragma unroll
      for (int e = 0; e < 4; ++e) {
        _Float16 h = (_Float16)vv[e];
        hv[e] = h;
        lv[e] = (_Float16)(vv[e] - (float)h);
      }
      int base = ((mtt * 8 + ks) << 10) + lane2 * 16 + j * 2;
      *(f16x4*)(lds + base) = hv;
      *(f16x4*)(lds + base + 4096) = lv;
    }
    __syncthreads();
#pragma unroll
    for (int ks = 0; ks < 4; ++ks) {
      f16x8 ah = *(const f16x8*)(lds + ((mt * 8 + ks) << 10) + l * 16);
      f16x8 al = *(const f16x8*)(lds + ((mt * 8 + 4 + ks) << 10) + l * 16);
      f16x8 bh = *(const f16x8*)(lds + 16384 + ((nt * 8 + ks) << 10) + l * 16);
      f16x8 bl = *(const f16x8*)(lds + 16384 + ((nt * 8 + 4 + ks) << 10) + l * 16);
      acc = __builtin_amdgcn_mfma_f32_32x32x16_f16(ah, bh, acc, 0, 0, 0);
      acc = __builtin_amdgcn_mfma_f32_32x32x16_f16(ah, bl, acc, 0, 0, 0);
      acc = __builtin_amdgcn_mfma_f32_32x32x16_f16(al, bh, acc, 0, 0, 0);
    }
    __syncthreads();
  }

  int col = cb + nt * 32 + (l & 31);
  float bv = bias[col];
#pragma unroll
  for (int r = 0; r < 16; ++r) {
    int row = rb + mt * 32 + (r & 3) + 8 * (r >> 2) + 4 * (l >> 5);
    C[(size_t)row * N + col] = acc[r] + bv;
  }
}

// ---------------------------------------------------------------------------
// Scorer: s = z . e_hat via fp16 MFMA, A(z)=hi/lo, B(e_hat)=hi only (2 MFMAs),
// fused per-row top-2 argmax. Grid (8 csplit, 64 rowblock), 256 thr = 4 waves.
// Block: 128 rows (wave w -> m-tile w) x 1024 codes in 4 chunks of 256;
// K=256 in 4 slices of 64. Per wave per k-step: 2 A reads + 8 B reads ->
// 16 MFMAs (512 B LDS-read per MFMA). LDS 64 KB: A 32K (4mt x 2prec x 4ks x
// 1KB), B 32K (8nt x 4ks x 1KB), staged via global_load_lds width=16.
// ---------------------------------------------------------------------------
__global__ __launch_bounds__(256, 2) void score_mfma(
    const _Float16* __restrict__ zfrag, const _Float16* __restrict__ efrag,
    unsigned long long* __restrict__ cand1, unsigned int* __restrict__ cand2) {
  __shared__ char lds[65536];
  const int tid = threadIdx.x;
  const int l = tid & 63;
  const int w = tid >> 6;
  const int csplit = blockIdx.x, rowblock = blockIdx.y;

  float b1[16], b2[16];
  int i1[16];
#pragma unroll
  for (int r = 0; r < 16; ++r) {
    b1[r] = -INFINITY;
    b2[r] = -INFINITY;
    i1[r] = 0;
  }

  for (int chunk = 0; chunk < 4; ++chunk) {
    f32x16_t acc[8];
#pragma unroll
    for (int j = 0; j < 8; ++j) acc[j] = (f32x16_t)0.0f;

    for (int s = 0; s < 4; ++s) {
#pragma unroll
      for (int i = 0; i < 16; ++i) {
        int c = i * 4 + w;  // 0..63
        const _Float16* src;
        if (c < 32) {  // A: ((mt*2+prec)*4+ks)
          int mt = c >> 3, prec = (c >> 2) & 1, ks = c & 3;
          int tile = rowblock * 4 + mt, ksg = s * 4 + ks;
          src = zfrag + (size_t)prec * (BATCH * LAT) +
                ((size_t)(tile * 16 + ksg) * 64 + l) * 8;
        } else {  // B: 32 + nt*4 + ks
          int j2 = c - 32;
          int nt = j2 >> 2, ks = j2 & 3;
          int tile = csplit * 32 + chunk * 8 + nt, ksg = s * 4 + ks;
          src = efrag + ((size_t)(tile * 16 + ksg) * 64 + l) * 8;
        }
        __builtin_amdgcn_global_load_lds((gu32_t*)src,
                                         (lu32_t*)(lds + (c << 10) + l * 16),
                                         16, 0, 0);
      }
      __syncthreads();
#pragma unroll
      for (int ks = 0; ks < 4; ++ks) {
        f16x8 ah = *(const f16x8*)(lds + ((w * 8 + ks) << 10) + l * 16);
        f16x8 al = *(const f16x8*)(lds + ((w * 8 + 4 + ks) << 10) + l * 16);
#pragma unroll
        for (int j = 0; j < 8; ++j) {
          f16x8 bh = *(const f16x8*)(lds + 32768 + ((j * 4 + ks) << 10) + l * 16);
          acc[j] = __builtin_amdgcn_mfma_f32_32x32x16_f16(ah, bh, acc[j], 0, 0, 0);
          acc[j] = __builtin_amdgcn_mfma_f32_32x32x16_f16(al, bh, acc[j], 0, 0, 0);
        }
      }
      __syncthreads();
    }
    // fold chunk (256 codes: 8 n-tiles x 32 cols) into running top-2
    int colbase = csplit * 1024 + chunk * 256 + (l & 31);
#pragma unroll
    for (int r = 0; r < 16; ++r) {
      float c1 = acc[0][r], c2 = -INFINITY;
      int cidx = colbase;
#pragma unroll
      for (int j = 1; j < 8; ++j) {
        float v = acc[j][r];
        if (v > c1) {
          c2 = c1;
          c1 = v;
          cidx = colbase + j * 32;
        } else {
          c2 = fmaxf(c2, v);
        }
      }
      float nb2 = fmaxf(fminf(b1[r], c1), fmaxf(b2[r], c2));
      if (c1 > b1[r] || (c1 == b1[r] && cidx < i1[r])) {
        b1[r] = c1;
        i1[r] = cidx;
      }
      b2[r] = nb2;
    }
  }

  // cross-lane top-2 merge over the 32 columns (ties -> lower idx)
#pragma unroll
  for (int r = 0; r < 16; ++r) {
    float v1 = b1[r], v2 = b2[r];
    int vi = i1[r];
#pragma unroll
    for (int m = 1; m < 32; m <<= 1) {
      float o1 = __shfl_xor(v1, m);
      int oi = __shfl_xor(vi, m);
      float o2 = __shfl_xor(v2, m);
      float n2v = fmaxf(fminf(v1, o1), fmaxf(v2, o2));
      if (o1 > v1 || (o1 == v1 && oi < vi)) {
        v1 = o1;
        vi = oi;
      }
      v2 = n2v;
    }
    if ((l & 31) == 0) {
      int row = rowblock * 128 + w * 32 + (r & 3) + 8 * (r >> 2) + 4 * (l >> 5);
      cand1[(size_t)row * 8 + csplit] =
          ((unsigned long long)ford(v1) << 32) |
          (unsigned long long)(unsigned int)(NEMB - 1 - vi);
      cand2[(size_t)row * 8 + csplit] = ford(v2);
    }
  }
}

// ---------------------------------------------------------------------------
// Per-row: merge 8 slots -> winner + runner-up -> margin; flag tight rows.
// ---------------------------------------------------------------------------
__global__ __launch_bounds__(256) void finalize1(
    const unsigned long long* __restrict__ cand1,
    const unsigned int* __restrict__ cand2, int* __restrict__ idxi,
    unsigned int* __restrict__ flags, unsigned int* __restrict__ flag_count,
    unsigned int* __restrict__ flag_list) {
  int row = blockIdx.x * 256 + threadIdx.x;
  unsigned long long best = 0;
  unsigned int second = 0;
  int bslot = 0;
#pragma unroll
  for (int s = 0; s < 8; ++s) {
    unsigned long long v = cand1[(size_t)row * 8 + s];
    unsigned int vs = (unsigned int)(v >> 32);
    if (v > best) {
      second = (unsigned int)(best >> 32);
      best = v;
      bslot = s;
    } else if (vs > second) {
      second = vs;
    }
  }
  unsigned int r2 = cand2[(size_t)row * 8 + bslot];
  if (r2 > second) second = r2;
  float s1 = funord((unsigned int)(best >> 32));
  float s2 = funord(second);
  int idx = NEMB - 1 - (int)(best & 0xFFFFFFFFull);
  idxi[row] = idx;
  unsigned int fl = ((s1 - s2) < TAU) ? 1u : 0u;
  flags[row] = fl;
  if (fl) {
    unsigned int p = atomicAdd(flag_count, 1u);
    flag_list[p] = row;
  }
}

// ---------------------------------------------------------------------------
// Exact (fp64) rescore of flagged rows over all codes.
// ---------------------------------------------------------------------------
__global__ __launch_bounds__(256) void rescore(
    const float* __restrict__ z, const float* __restrict__ emb,
    const unsigned int* __restrict__ flag_list,
    const unsigned int* __restrict__ flag_count,
    unsigned long long* __restrict__ packed_rescore) {
  __shared__ float e_s[32][260];
  __shared__ double n2_s[32];
  __shared__ unsigned long long red[32];
  const int tid = threadIdx.x;
  const int cbase = blockIdx.x * 32;

  for (int t = tid; t < 32 * 64; t += 256) {
    int r = t >> 6, c4 = t & 63;
    float4 v = *(const float4*)&emb[(size_t)(cbase + r) * 256 + 4 * c4];
    *(float4*)&e_s[r][4 * c4] = v;
  }
  __syncthreads();

  const int code = tid >> 3, part = tid & 7;
  {
    double n2 = 0;
#pragma unroll 8
    for (int k = 0; k < 32; ++k) {
      double e = e_s[code][part * 32 + k];
      n2 += e * e;
    }
    for (int m = 1; m < 8; m <<= 1) n2 += __shfl_xor(n2, m);
    if (part == 0) n2_s[code] = n2;
  }
  __syncthreads();

  unsigned int cnt = *flag_count;
  for (unsigned int f = 0; f < cnt; ++f) {
    int row = (int)flag_list[f];
    const float* zr = z + (size_t)row * 256;
    double acc = 0;
#pragma unroll 8
    for (int k = 0; k < 32; ++k)
      acc += (double)e_s[code][part * 32 + k] * (double)zr[part * 32 + k];
    for (int m = 1; m < 8; m <<= 1) acc += __shfl_xor(acc, m);
    if (part == 0) {
      double s = acc / sqrt(n2_s[code]);
      float sf = (float)s;
      red[code] = ((unsigned long long)ford(sf) << 32) |
                  (unsigned long long)(unsigned int)(NEMB - 1 - (cbase + code));
    }
    __syncthreads();
    if (tid == 0) {
      unsigned long long b = red[0];
      for (int c = 1; c < 32; ++c)
        if (red[c] > b) b = red[c];
      atomicMax(&packed_rescore[row], b);
    }
    __syncthreads();
  }
}

// ---------------------------------------------------------------------------
// Final idx (float) + z_q gather. One wave per row.
// ---------------------------------------------------------------------------
__global__ __launch_bounds__(256) void gather_out(
    const int* __restrict__ idxi, const unsigned int* __restrict__ flags,
    const unsigned long long* __restrict__ packed_rescore,
    const float* __restrict__ emb, float* __restrict__ zq,
    float* __restrict__ idx_out) {
  int row = blockIdx.x * 4 + (threadIdx.x >> 6);
  int lane = threadIdx.x & 63;
  int idx = idxi[row];
  if (flags[row])
    idx = NEMB - 1 - (int)(packed_rescore[row] & 0xFFFFFFFFull);
  if (lane == 0) idx_out[row] = (float)idx;
  const float4* src = (const float4*)(emb + (size_t)idx * 256);
  float4* dst = (float4*)(zq + (size_t)row * 256);
  dst[lane] = src[lane];
}

// ---------------------------------------------------------------------------
extern "C" void kernel_launch(void* const* d_in, const int* in_sizes, int n_in,
                              void* d_out, int out_size, void* d_ws,
                              size_t ws_size, hipStream_t stream) {
  (void)in_sizes; (void)n_in; (void)out_size; (void)ws_size;
  const float* x     = (const float*)d_in[0];
  const float* enc_w = (const float*)d_in[1];
  const float* enc_b = (const float*)d_in[2];
  const float* emb   = (const float*)d_in[3];
  const float* dec_w = (const float*)d_in[4];
  const float* dec_b = (const float*)d_in[5];

  float* out     = (float*)d_out;
  float* x_recon = out;                               // 8192*1024
  float* z_out   = x_recon + (size_t)BATCH * IN_DIM;  // 8192*256
  float* zq_out  = z_out + (size_t)BATCH * LAT;       // 8192*256
  float* idx_out = zq_out + (size_t)BATCH * LAT;      // 8192 (as float)

  char* ws = (char*)d_ws;
  float* inv_norm = (float*)ws;                                    // 32 KB
  unsigned int* flags = (unsigned int*)(ws + 32768);               // 32 KB
  int* idxi = (int*)(ws + 65536);                                  // 32 KB
  unsigned int* flag_count = (unsigned int*)(ws + 98304);          // (zeroed)
  unsigned long long* packed_rescore =
      (unsigned long long*)(ws + 98432);                           // 64 KB (zeroed)
  unsigned int* flag_list = (unsigned int*)(ws + 163968);          // 32 KB
  unsigned long long* cand1 = (unsigned long long*)(ws + 262144);  // 512 KB
  unsigned int* cand2 = (unsigned int*)(ws + 786432);              // 256 KB
  _Float16* wfrag  = (_Float16*)(ws + 1048576);                    // 1 MB hi+lo
  _Float16* dwfrag = (_Float16*)(ws + 2097152);                    // 1 MB hi+lo
  _Float16* efrag  = (_Float16*)(ws + 3145728);                    // 4 MB hi only
  _Float16* zfrag  = (_Float16*)(ws + 7340032);                    // 8 MB hi+lo

  hipMemsetAsync(ws + 98304, 0, 128 + 65536, stream);

  emb_norms<<<NEMB / 4, 256, 0, stream>>>(emb, inv_norm);
  // weight + codebook fragment buffers
  split16<<<128, 256, 0, stream>>>(enc_w, (const float*)nullptr, wfrag,
                                   (size_t)LAT * IN_DIM, IN_DIM / 16, 1);
  split16<<<128, 256, 0, stream>>>(dec_w, (const float*)nullptr, dwfrag,
                                   (size_t)IN_DIM * LAT, LAT / 16, 1);
  split16<<<1024, 256, 0, stream>>>(emb, inv_norm, efrag, 0, LAT / 16, 0);

  // encoder: z = x @ enc_w^T + enc_b
  gemm16<<<dim3(LAT / 64, BATCH / 64), 256, 0, stream>>>(
      x, wfrag, (size_t)LAT * IN_DIM, enc_b, z_out, BATCH, LAT, IN_DIM);

  split16<<<1024, 256, 0, stream>>>(z_out, (const float*)nullptr, zfrag,
                                    (size_t)BATCH * LAT, LAT / 16, 1);

  // fused score + top-2 argmax
  score_mfma<<<dim3(8, 64), 256, 0, stream>>>(zfrag, efrag, cand1, cand2);

  finalize1<<<32, 256, 0, stream>>>(cand1, cand2, idxi, flags, flag_count,
                                    flag_list);
  rescore<<<256, 256, 0, stream>>>(z_out, emb, flag_list, flag_count,
                                   packed_rescore);
  gather_out<<<BATCH / 4, 256, 0, stream>>>(idxi, flags, packed_rescore, emb,
                                            zq_out, idx_out);

  // decoder: x_recon = z_q @ dec_w^T + dec_b
  gemm16<<<dim3(IN_DIM / 64, BATCH / 64), 256, 0, stream>>>(
      zq_out, dwfrag, (size_t)IN_DIM * LAT, dec_b, x_recon, BATCH, IN_DIM, LAT);
}

// Round 4
// 419.477 us; speedup vs baseline: 1.3534x; 1.3534x over previous
//
#include <hip/hip_runtime.h>
#include <math.h>

// Problem constants
#define BATCH   8192
#define IN_DIM  1024
#define LAT     256
#define NEMB    8192

#define TAU 3e-3f   // flag margin; score err sigma ~2.8e-4 (fp16-B rounding), TAU ~ 10 sigma

typedef _Float16 f16x8 __attribute__((ext_vector_type(8)));
typedef _Float16 f16x4 __attribute__((ext_vector_type(4)));
typedef float f32x16_t __attribute__((ext_vector_type(16)));

typedef __attribute__((address_space(1))) const unsigned int gu32_t;
typedef __attribute__((address_space(3))) unsigned int lu32_t;

// order-preserving float<->u32 transform
__device__ __forceinline__ unsigned int ford(float x) {
  unsigned int u = __float_as_uint(x);
  return (u & 0x80000000u) ? ~u : (u | 0x80000000u);
}
__device__ __forceinline__ float funord(unsigned int t) {
  unsigned int u = (t & 0x80000000u) ? (t & 0x7FFFFFFFu) : ~t;
  return __uint_as_float(u);
}

// ---------------------------------------------------------------------------
// Per-code inverse norms: one wave per embedding row.
// ---------------------------------------------------------------------------
__global__ __launch_bounds__(256) void emb_norms(
    const float* __restrict__ emb, float* __restrict__ inv_norm) {
  int row = blockIdx.x * 4 + (threadIdx.x >> 6);
  int lane = threadIdx.x & 63;
  const float* p = emb + (size_t)row * LAT;
  float s = 0.f;
#pragma unroll
  for (int t = 0; t < 4; ++t) {
    float v = p[lane + 64 * t];
    s += v * v;
  }
#pragma unroll
  for (int off = 32; off; off >>= 1) s += __shfl_xor(s, off);
  if (lane == 0) inv_norm[row] = 1.0f / sqrtf(s);
}

// ---------------------------------------------------------------------------
// Split fp32 [R x K] (optionally scaled per-row) into fp16 hi (+ optional lo)
// in MFMA-32x32x16 fragment order:
//   frag block g=(tile,kb): lane l -> elem [tile*32+(l&31)][kb*16+(l>>5)*8+j]
//   stored at dst[(g*64+l)*8 + j]; lo at dst + lo_off (= R*K) if write_lo.
// ---------------------------------------------------------------------------
__global__ __launch_bounds__(256) void split16(
    const float* __restrict__ src, const float* __restrict__ inv_norm,
    _Float16* __restrict__ dst, size_t lo_off, int KD, int write_lo) {
  int gw = (blockIdx.x * 256 + threadIdx.x) >> 6;
  int l = threadIdx.x & 63;
  int tile = gw / KD, kb = gw % KD;
  int row = tile * 32 + (l & 31);
  int k = kb * 16 + (l >> 5) * 8;
  const float* p = src + (size_t)row * (KD * 16) + k;
  float scale = inv_norm ? inv_norm[row] : 1.0f;
  f16x8 h, lo;
#pragma unroll
  for (int j = 0; j < 8; ++j) {
    float v = p[j] * scale;
    _Float16 hh = (_Float16)v;
    h[j] = hh;
    lo[j] = (_Float16)(v - (float)hh);
  }
  size_t o = ((size_t)gw * 64 + l) * 8;
  *(f16x8*)(dst + o) = h;
  if (write_lo) *(f16x8*)(dst + lo_off + o) = lo;
}

// ---------------------------------------------------------------------------
// Split-fp16 MFMA GEMM, BOTH operands pre-split in fragment order.
// C[M][N] = A@B^T + bias. Block 64x64, 4 waves (mt=w&1, nt=w>>1), K-slice 64.
// All staging via global_load_lds width=16. 3 MFMAs per k-step.
// ---------------------------------------------------------------------------
__global__ __launch_bounds__(256) void gemm16_frag(
    const _Float16* __restrict__ Afrag, size_t a_lo_off,
    const _Float16* __restrict__ Bfrag, size_t b_lo_off,
    const float* __restrict__ bias, float* __restrict__ C, int N, int K) {
  __shared__ char lds[32768];  // A chunks [0,16K): (mt*8+prec*4+ks); B at 16K
  const int tid = threadIdx.x;
  const int l = tid & 63;
  const int w = tid >> 6;
  const int mt = w & 1, nt = w >> 1;
  const int rb = blockIdx.y * 64, cb = blockIdx.x * 64;
  const int KD = K >> 4;

  f32x16_t acc = (f32x16_t)0.0f;

  for (int s = 0; s < (K >> 6); ++s) {
#pragma unroll
    for (int i = 0; i < 8; ++i) {
      int c = i * 4 + w;  // 0..31
      int isB = c >> 4;
      int cc = c & 15;
      int t32 = cc >> 3, prec = (cc >> 2) & 1, ks = cc & 3;
      int tile = ((isB ? cb : rb) >> 5) + t32;
      int kb = s * 4 + ks;
      const _Float16* base = isB ? Bfrag : Afrag;
      size_t lo = isB ? b_lo_off : a_lo_off;
      const _Float16* src =
          base + (size_t)prec * lo + ((size_t)(tile * KD + kb) * 64 + l) * 8;
      __builtin_amdgcn_global_load_lds((gu32_t*)src,
                                       (lu32_t*)(lds + (c << 10) + l * 16),
                                       16, 0, 0);
    }
    __syncthreads();
#pragma unroll
    for (int ks = 0; ks < 4; ++ks) {
      f16x8 ah = *(const f16x8*)(lds + ((mt * 8 + ks) << 10) + l * 16);
      f16x8 al = *(const f16x8*)(lds + ((mt * 8 + 4 + ks) << 10) + l * 16);
      f16x8 bh = *(const f16x8*)(lds + 16384 + ((nt * 8 + ks) << 10) + l * 16);
      f16x8 bl = *(const f16x8*)(lds + 16384 + ((nt * 8 + 4 + ks) << 10) + l * 16);
      acc = __builtin_amdgcn_mfma_f32_32x32x16_f16(ah, bh, acc, 0, 0, 0);
      acc = __builtin_amdgcn_mfma_f32_32x32x16_f16(ah, bl, acc, 0, 0, 0);
      acc = __builtin_amdgcn_mfma_f32_32x32x16_f16(al, bh, acc, 0, 0, 0);
    }
    __syncthreads();
  }

  int col = cb + nt * 32 + (l & 31);
  float bv = bias[col];
#pragma unroll
  for (int r = 0; r < 16; ++r) {
    int row = rb + mt * 32 + (r & 3) + 8 * (r >> 2) + 4 * (l >> 5);
    C[(size_t)row * N + col] = acc[r] + bv;
  }
}

// ---------------------------------------------------------------------------
// Fallback GEMM (A fp32, split to fp16 hi/lo in-kernel): as round 3.
// ---------------------------------------------------------------------------
__global__ __launch_bounds__(256) void gemm16(
    const float* __restrict__ A, const _Float16* __restrict__ Bfrag,
    size_t b_lo_off, const float* __restrict__ bias, float* __restrict__ C,
    int M, int N, int K) {
  __shared__ char lds[32768];
  const int tid = threadIdx.x;
  const int l = tid & 63;
  const int w = tid >> 6;
  const int mt = w & 1, nt = w >> 1;
  const int rb = blockIdx.y * 64, cb = blockIdx.x * 64;
  const int KD = K >> 4;

  f32x16_t acc = (f32x16_t)0.0f;

  for (int s = 0; s < (K >> 6); ++s) {
#pragma unroll
    for (int i = 0; i < 4; ++i) {
      int c = i * 4 + w;  // 0..15: ((bnt*2+prec)*4+ks)
      int bnt = c >> 3, prec = (c >> 2) & 1, ks = c & 3;
      int tile = (cb >> 5) + bnt, ksg = s * 4 + ks;
      const _Float16* src = Bfrag + (size_t)prec * b_lo_off +
                            ((size_t)(tile * KD + ksg) * 64 + l) * 8;
      __builtin_amdgcn_global_load_lds((gu32_t*)src,
                                       (lu32_t*)(lds + 16384 + (c << 10) + l * 16),
                                       16, 0, 0);
    }
#pragma unroll
    for (int t = 0; t < 4; ++t) {
      int flat = t * 256 + tid;
      int r = flat >> 4, c4 = flat & 15;
      float4 v = *(const float4*)&A[(size_t)(rb + r) * K + s * 64 + 4 * c4];
      int kk = 4 * c4;
      int ks = kk >> 4, j = kk & 7;
      int lane2 = (r & 31) + 32 * ((kk >> 3) & 1);
      int mtt = r >> 5;
      f16x4 hv, lv;
      float vv[4] = {v.x, v.y, v.z, v.w};
#pragma unroll
      for (int e = 0; e < 4; ++e) {
        _Float16 h = (_Float16)vv[e];
        hv[e] = h;
        lv[e] = (_Float16)(vv[e] - (float)h);
      }
      int base = ((mtt * 8 + ks) << 10) + lane2 * 16 + j * 2;
      *(f16x4*)(lds + base) = hv;
      *(f16x4*)(lds + base + 4096) = lv;
    }
    __syncthreads();
#pragma unroll
    for (int ks = 0; ks < 4; ++ks) {
      f16x8 ah = *(const f16x8*)(lds + ((mt * 8 + ks) << 10) + l * 16);
      f16x8 al = *(const f16x8*)(lds + ((mt * 8 + 4 + ks) << 10) + l * 16);
      f16x8 bh = *(const f16x8*)(lds + 16384 + ((nt * 8 + ks) << 10) + l * 16);
      f16x8 bl = *(const f16x8*)(lds + 16384 + ((nt * 8 + 4 + ks) << 10) + l * 16);
      acc = __builtin_amdgcn_mfma_f32_32x32x16_f16(ah, bh, acc, 0, 0, 0);
      acc = __builtin_amdgcn_mfma_f32_32x32x16_f16(ah, bl, acc, 0, 0, 0);
      acc = __builtin_amdgcn_mfma_f32_32x32x16_f16(al, bh, acc, 0, 0, 0);
    }
    __syncthreads();
  }

  int col = cb + nt * 32 + (l & 31);
  float bv = bias[col];
#pragma unroll
  for (int r = 0; r < 16; ++r) {
    int row = rb + mt * 32 + (r & 3) + 8 * (r >> 2) + 4 * (l >> 5);
    C[(size_t)row * N + col] = acc[r] + bv;
  }
}

// ---------------------------------------------------------------------------
// Scorer: s = z . e_hat via fp16 MFMA, A(z)=hi/lo, B(e_hat)=hi only (2 MFMAs),
// fused per-row top-2 argmax. Grid (8 csplit, 64 rowblock), 256 thr = 4 waves.
// ---------------------------------------------------------------------------
__global__ __launch_bounds__(256, 2) void score_mfma(
    const _Float16* __restrict__ zfrag, const _Float16* __restrict__ efrag,
    unsigned long long* __restrict__ cand1, unsigned int* __restrict__ cand2) {
  __shared__ char lds[65536];
  const int tid = threadIdx.x;
  const int l = tid & 63;
  const int w = tid >> 6;
  const int csplit = blockIdx.x, rowblock = blockIdx.y;

  float b1[16], b2[16];
  int i1[16];
#pragma unroll
  for (int r = 0; r < 16; ++r) {
    b1[r] = -INFINITY;
    b2[r] = -INFINITY;
    i1[r] = 0;
  }

  for (int chunk = 0; chunk < 4; ++chunk) {
    f32x16_t acc[8];
#pragma unroll
    for (int j = 0; j < 8; ++j) acc[j] = (f32x16_t)0.0f;

    for (int s = 0; s < 4; ++s) {
#pragma unroll
      for (int i = 0; i < 16; ++i) {
        int c = i * 4 + w;  // 0..63
        const _Float16* src;
        if (c < 32) {  // A: ((mt*2+prec)*4+ks)
          int mt = c >> 3, prec = (c >> 2) & 1, ks = c & 3;
          int tile = rowblock * 4 + mt, ksg = s * 4 + ks;
          src = zfrag + (size_t)prec * (BATCH * LAT) +
                ((size_t)(tile * 16 + ksg) * 64 + l) * 8;
        } else {  // B: 32 + nt*4 + ks
          int j2 = c - 32;
          int nt = j2 >> 2, ks = j2 & 3;
          int tile = csplit * 32 + chunk * 8 + nt, ksg = s * 4 + ks;
          src = efrag + ((size_t)(tile * 16 + ksg) * 64 + l) * 8;
        }
        __builtin_amdgcn_global_load_lds((gu32_t*)src,
                                         (lu32_t*)(lds + (c << 10) + l * 16),
                                         16, 0, 0);
      }
      __syncthreads();
#pragma unroll
      for (int ks = 0; ks < 4; ++ks) {
        f16x8 ah = *(const f16x8*)(lds + ((w * 8 + ks) << 10) + l * 16);
        f16x8 al = *(const f16x8*)(lds + ((w * 8 + 4 + ks) << 10) + l * 16);
#pragma unroll
        for (int j = 0; j < 8; ++j) {
          f16x8 bh = *(const f16x8*)(lds + 32768 + ((j * 4 + ks) << 10) + l * 16);
          acc[j] = __builtin_amdgcn_mfma_f32_32x32x16_f16(ah, bh, acc[j], 0, 0, 0);
          acc[j] = __builtin_amdgcn_mfma_f32_32x32x16_f16(al, bh, acc[j], 0, 0, 0);
        }
      }
      __syncthreads();
    }
    int colbase = csplit * 1024 + chunk * 256 + (l & 31);
#pragma unroll
    for (int r = 0; r < 16; ++r) {
      float c1 = acc[0][r], c2 = -INFINITY;
      int cidx = colbase;
#pragma unroll
      for (int j = 1; j < 8; ++j) {
        float v = acc[j][r];
        if (v > c1) {
          c2 = c1;
          c1 = v;
          cidx = colbase + j * 32;
        } else {
          c2 = fmaxf(c2, v);
        }
      }
      float nb2 = fmaxf(fminf(b1[r], c1), fmaxf(b2[r], c2));
      if (c1 > b1[r] || (c1 == b1[r] && cidx < i1[r])) {
        b1[r] = c1;
        i1[r] = cidx;
      }
      b2[r] = nb2;
    }
  }

#pragma unroll
  for (int r = 0; r < 16; ++r) {
    float v1 = b1[r], v2 = b2[r];
    int vi = i1[r];
#pragma unroll
    for (int m = 1; m < 32; m <<= 1) {
      float o1 = __shfl_xor(v1, m);
      int oi = __shfl_xor(vi, m);
      float o2 = __shfl_xor(v2, m);
      float n2v = fmaxf(fminf(v1, o1), fmaxf(v2, o2));
      if (o1 > v1 || (o1 == v1 && oi < vi)) {
        v1 = o1;
        vi = oi;
      }
      v2 = n2v;
    }
    if ((l & 31) == 0) {
      int row = rowblock * 128 + w * 32 + (r & 3) + 8 * (r >> 2) + 4 * (l >> 5);
      cand1[(size_t)row * 8 + csplit] =
          ((unsigned long long)ford(v1) << 32) |
          (unsigned long long)(unsigned int)(NEMB - 1 - vi);
      cand2[(size_t)row * 8 + csplit] = ford(v2);
    }
  }
}

// ---------------------------------------------------------------------------
// Per-row: merge 8 slots -> winner + runner-up -> margin; flag tight rows.
// ---------------------------------------------------------------------------
__global__ __launch_bounds__(256) void finalize1(
    const unsigned long long* __restrict__ cand1,
    const unsigned int* __restrict__ cand2, int* __restrict__ idxi,
    unsigned int* __restrict__ flags, unsigned int* __restrict__ flag_count,
    unsigned int* __restrict__ flag_list) {
  int row = blockIdx.x * 256 + threadIdx.x;
  unsigned long long best = 0;
  unsigned int second = 0;
  int bslot = 0;
#pragma unroll
  for (int s = 0; s < 8; ++s) {
    unsigned long long v = cand1[(size_t)row * 8 + s];
    unsigned int vs = (unsigned int)(v >> 32);
    if (v > best) {
      second = (unsigned int)(best >> 32);
      best = v;
      bslot = s;
    } else if (vs > second) {
      second = vs;
    }
  }
  unsigned int r2 = cand2[(size_t)row * 8 + bslot];
  if (r2 > second) second = r2;
  float s1 = funord((unsigned int)(best >> 32));
  float s2 = funord(second);
  int idx = NEMB - 1 - (int)(best & 0xFFFFFFFFull);
  idxi[row] = idx;
  unsigned int fl = ((s1 - s2) < TAU) ? 1u : 0u;
  flags[row] = fl;
  if (fl) {
    unsigned int p = atomicAdd(flag_count, 1u);
    flag_list[p] = row;
  }
}

// ---------------------------------------------------------------------------
// Exact fp32 rescore of flagged rows. Block owns 32 codes IN REGISTERS
// (8 float4/thread), z row staged in LDS with part-staggered pitch-36 layout
// (conflict-free b128 reads). 2 rows per iteration, in-wave shuffle reduce,
// one packed atomicMax per row. Thread map: code = w*8+(l&7), part p = l>>3.
// ---------------------------------------------------------------------------
__global__ __launch_bounds__(256) void rescore(
    const float* __restrict__ z, const float* __restrict__ emb,
    const float* __restrict__ inv_norm,
    const unsigned int* __restrict__ flag_list,
    const unsigned int* __restrict__ flag_count,
    unsigned long long* __restrict__ packed_rescore) {
  __shared__ float z_s[2][292];  // [p*36 + j] staggered layout (8*36=288)
  __shared__ unsigned long long red[64];
  const int tid = threadIdx.x;
  const int l = tid & 63;
  const int w = tid >> 6;
  const int cl = l & 7;
  const int p = l >> 3;
  const int code = w * 8 + cl;  // 0..31
  const int cbase = blockIdx.x * 32;

  float4 e4[8];
  const float* ebase = emb + (size_t)(cbase + code) * 256 + p * 32;
#pragma unroll
  for (int j = 0; j < 8; ++j) e4[j] = *(const float4*)&ebase[4 * j];
  const float inv = inv_norm[cbase + code];
  const unsigned int lowbits = (unsigned int)(NEMB - 1 - (cbase + code));

  unsigned int cnt = *flag_count;
  for (unsigned int f = 0; f < cnt; f += 2) {
    int row0 = (int)flag_list[f];
    int row1 = (f + 1 < cnt) ? (int)flag_list[f + 1] : row0;
    __syncthreads();
    if (tid < 128) {
      int half = tid >> 6, t = tid & 63;
      int k0 = t * 4;                       // element index 0..252
      int addr = k0 + 4 * (k0 >> 5);        // staggered address
      const float* zp = z + (size_t)(half ? row1 : row0) * 256 + k0;
      *(float4*)&z_s[half][addr] = *(const float4*)zp;
    }
    __syncthreads();
    float a0 = 0.f, a1 = 0.f;
#pragma unroll
    for (int j = 0; j < 8; ++j) {
      float4 z0 = *(const float4*)&z_s[0][p * 36 + 4 * j];
      float4 z1 = *(const float4*)&z_s[1][p * 36 + 4 * j];
      a0 += e4[j].x * z0.x + e4[j].y * z0.y + e4[j].z * z0.z + e4[j].w * z0.w;
      a1 += e4[j].x * z1.x + e4[j].y * z1.y + e4[j].z * z1.z + e4[j].w * z1.w;
    }
#pragma unroll
    for (int m = 8; m < 64; m <<= 1) {
      a0 += __shfl_xor(a0, m);
      a1 += __shfl_xor(a1, m);
    }
    if (l < 8)
      red[w * 8 + cl] = ((unsigned long long)ford(a0 * inv) << 32) | lowbits;
    else if (l < 16)
      red[32 + w * 8 + cl] = ((unsigned long long)ford(a1 * inv) << 32) | lowbits;
    __syncthreads();
    if (w == 0) {
      unsigned long long v = red[l];
#pragma unroll
      for (int m = 1; m < 32; m <<= 1) {
        unsigned long long o = __shfl_xor(v, m);
        if (o > v) v = o;
      }
      if (l == 0) atomicMax(&packed_rescore[row0], v);
      if (l == 32) atomicMax(&packed_rescore[row1], v);
    }
  }
}

// ---------------------------------------------------------------------------
// Final idx (float) + z_q gather + (optional) zq hi/lo fragment split.
// Block = 32 rows.
// ---------------------------------------------------------------------------
__global__ __launch_bounds__(256) void gather_split(
    const int* __restrict__ idxi, const unsigned int* __restrict__ flags,
    const unsigned long long* __restrict__ packed_rescore,
    const float* __restrict__ emb, float* __restrict__ zq,
    float* __restrict__ idx_out, _Float16* __restrict__ zqfrag,
    size_t lo_off, int use_frag) {
  __shared__ float zrow[32][260];
  __shared__ int idxs[32];
  const int tid = threadIdx.x;
  const int tile = blockIdx.x;
  if (tid < 32) {
    int row = tile * 32 + tid;
    int idx = idxi[row];
    if (flags[row]) idx = NEMB - 1 - (int)(packed_rescore[row] & 0xFFFFFFFFull);
    idxs[tid] = idx;
    idx_out[row] = (float)idx;
  }
  __syncthreads();
#pragma unroll
  for (int t = 0; t < 8; ++t) {
    int flat = t * 256 + tid;
    int r = flat >> 6, c4 = flat & 63;
    float4 v = *(const float4*)&emb[(size_t)idxs[r] * 256 + 4 * c4];
    *(float4*)&zrow[r][4 * c4] = v;
    *(float4*)&zq[(size_t)(tile * 32 + r) * 256 + 4 * c4] = v;
  }
  if (use_frag) {
    __syncthreads();
#pragma unroll
    for (int t = 0; t < 4; ++t) {
      int flat = t * 256 + tid;  // 16 frag blocks x 64 lanes
      int fb = flat >> 6, fl = flat & 63;
      int r = fl & 31, k0 = fb * 16 + (fl >> 5) * 8;
      float4 v0 = *(const float4*)&zrow[r][k0];
      float4 v1 = *(const float4*)&zrow[r][k0 + 4];
      float vv[8] = {v0.x, v0.y, v0.z, v0.w, v1.x, v1.y, v1.z, v1.w};
      f16x8 hv, lv;
#pragma unroll
      for (int j = 0; j < 8; ++j) {
        _Float16 h = (_Float16)vv[j];
        hv[j] = h;
        lv[j] = (_Float16)(vv[j] - (float)h);
      }
      size_t g = ((size_t)(tile * 16 + fb) * 64 + fl) * 8;
      *(f16x8*)(zqfrag + g) = hv;
      *(f16x8*)(zqfrag + lo_off + g) = lv;
    }
  }
}

// ---------------------------------------------------------------------------
extern "C" void kernel_launch(void* const* d_in, const int* in_sizes, int n_in,
                              void* d_out, int out_size, void* d_ws,
                              size_t ws_size, hipStream_t stream) {
  (void)in_sizes; (void)n_in; (void)out_size;
  const float* x     = (const float*)d_in[0];
  const float* enc_w = (const float*)d_in[1];
  const float* enc_b = (const float*)d_in[2];
  const float* emb   = (const float*)d_in[3];
  const float* dec_w = (const float*)d_in[4];
  const float* dec_b = (const float*)d_in[5];

  float* out     = (float*)d_out;
  float* x_recon = out;                               // 8192*1024
  float* z_out   = x_recon + (size_t)BATCH * IN_DIM;  // 8192*256
  float* zq_out  = z_out + (size_t)BATCH * LAT;       // 8192*256
  float* idx_out = zq_out + (size_t)BATCH * LAT;      // 8192 (as float)

  char* ws = (char*)d_ws;
  float* inv_norm = (float*)ws;                                    // 32 KB
  unsigned int* flags = (unsigned int*)(ws + 32768);               // 32 KB
  int* idxi = (int*)(ws + 65536);                                  // 32 KB
  unsigned int* flag_count = (unsigned int*)(ws + 98304);          // (zeroed)
  unsigned long long* packed_rescore =
      (unsigned long long*)(ws + 98432);                           // 64 KB (zeroed)
  unsigned int* flag_list = (unsigned int*)(ws + 163968);          // 32 KB
  unsigned long long* cand1 = (unsigned long long*)(ws + 262144);  // 512 KB
  unsigned int* cand2 = (unsigned int*)(ws + 786432);              // 256 KB
  _Float16* wfrag  = (_Float16*)(ws + 1048576);                    // 1 MB hi+lo
  _Float16* dwfrag = (_Float16*)(ws + 2097152);                    // 1 MB hi+lo
  _Float16* efrag  = (_Float16*)(ws + 3145728);                    // 4 MB hi only
  _Float16* zfrag  = (_Float16*)(ws + 7340032);                    // 8 MB hi+lo
  _Float16* zqfrag = (_Float16*)(ws + 15728640);                   // 8 MB hi+lo
  _Float16* xfrag  = (_Float16*)(ws + 24117248);                   // 32 MB hi+lo

  const bool has_zq = ws_size >= 24117248ull;
  const bool has_x  = ws_size >= 57671680ull;

  hipMemsetAsync(ws + 98304, 0, 128 + 65536, stream);

  emb_norms<<<NEMB / 4, 256, 0, stream>>>(emb, inv_norm);
  split16<<<128, 256, 0, stream>>>(enc_w, (const float*)nullptr, wfrag,
                                   (size_t)LAT * IN_DIM, IN_DIM / 16, 1);
  split16<<<128, 256, 0, stream>>>(dec_w, (const float*)nullptr, dwfrag,
                                   (size_t)IN_DIM * LAT, LAT / 16, 1);
  split16<<<1024, 256, 0, stream>>>(emb, inv_norm, efrag, 0, LAT / 16, 0);

  // encoder: z = x @ enc_w^T + enc_b
  if (has_x) {
    split16<<<4096, 256, 0, stream>>>(x, (const float*)nullptr, xfrag,
                                      (size_t)BATCH * IN_DIM, IN_DIM / 16, 1);
    gemm16_frag<<<dim3(LAT / 64, BATCH / 64), 256, 0, stream>>>(
        xfrag, (size_t)BATCH * IN_DIM, wfrag, (size_t)LAT * IN_DIM, enc_b,
        z_out, LAT, IN_DIM);
  } else {
    gemm16<<<dim3(LAT / 64, BATCH / 64), 256, 0, stream>>>(
        x, wfrag, (size_t)LAT * IN_DIM, enc_b, z_out, BATCH, LAT, IN_DIM);
  }

  split16<<<1024, 256, 0, stream>>>(z_out, (const float*)nullptr, zfrag,
                                    (size_t)BATCH * LAT, LAT / 16, 1);

  // fused score + top-2 argmax
  score_mfma<<<dim3(8, 64), 256, 0, stream>>>(zfrag, efrag, cand1, cand2);

  finalize1<<<32, 256, 0, stream>>>(cand1, cand2, idxi, flags, flag_count,
                                    flag_list);
  rescore<<<256, 256, 0, stream>>>(z_out, emb, inv_norm, flag_list, flag_count,
                                   packed_rescore);

  // idx + z_q gather (+ zq frag split for decoder)
  gather_split<<<BATCH / 32, 256, 0, stream>>>(
      idxi, flags, packed_rescore, emb, zq_out, idx_out,
      has_zq ? zqfrag : (_Float16*)nullptr, (size_t)BATCH * LAT,
      has_zq ? 1 : 0);

  // decoder: x_recon = z_q @ dec_w^T + dec_b
  if (has_zq) {
    gemm16_frag<<<dim3(IN_DIM / 64, BATCH / 64), 256, 0, stream>>>(
        zqfrag, (size_t)BATCH * LAT, dwfrag, (size_t)IN_DIM * LAT, dec_b,
        x_recon, IN_DIM, LAT);
  } else {
    gemm16<<<dim3(IN_DIM / 64, BATCH / 64), 256, 0, stream>>>(
        zq_out, dwfrag, (size_t)IN_DIM * LAT, dec_b, x_recon, BATCH, IN_DIM,
        LAT);
  }
}